// Round 1
// baseline (1955.475 us; speedup 1.0000x reference)
//
#include <hip/hip_runtime.h>
#include <stdint.h>

#define T_STEPS 1024
#define HDIM    128
#define NT      512   // threads per block = 4*H gate rows

typedef __bf16 v2bf __attribute__((ext_vector_type(2)));

// d = a0*b0 + a1*b1 + c, operands are bf16 pairs packed in uint32 (elem0 = low 16)
__device__ __forceinline__ float dot2_bf16(uint32_t a, uint32_t b, float c) {
#if defined(__HIP_DEVICE_COMPILE__) && __has_builtin(__builtin_amdgcn_fdot2_f32_bf16)
    union U { uint32_t u; v2bf v; };
    U ua, ub; ua.u = a; ub.u = b;
    return __builtin_amdgcn_fdot2_f32_bf16(ua.v, ub.v, c, false);
#else
    float a0 = __uint_as_float(a << 16);
    float a1 = __uint_as_float(a & 0xFFFF0000u);
    float b0 = __uint_as_float(b << 16);
    float b1 = __uint_as_float(b & 0xFFFF0000u);
    return fmaf(a1, b1, fmaf(a0, b0, c));
#endif
}

__device__ __forceinline__ uint16_t f2bf(float f) {  // round-to-nearest-even
    uint32_t u = __float_as_uint(f);
    u += 0x7FFFu + ((u >> 16) & 1u);
    return (uint16_t)(u >> 16);
}
__device__ __forceinline__ uint32_t pack2(float lo, float hi) {
    return (uint32_t)f2bf(lo) | ((uint32_t)f2bf(hi) << 16);
}
__device__ __forceinline__ float sigmoidf_(float x) {
    return 1.0f / (1.0f + __expf(-x));
}
__device__ __forceinline__ float tanhf_(float x) {
    return 1.0f - 2.0f / (__expf(2.0f * x) + 1.0f);
}

__global__ __launch_bounds__(NT) void lstm_persistent(
    const float* __restrict__ x,
    const float* __restrict__ W_ih1, const float* __restrict__ W_hh1,
    const float* __restrict__ b_ih1, const float* __restrict__ b_hh1,
    const float* __restrict__ W_ih2, const float* __restrict__ W_hh2,
    const float* __restrict__ b_ih2, const float* __restrict__ b_hh2,
    const float* __restrict__ W_out, const float* __restrict__ b_out,
    float* __restrict__ out)
{
    const int b   = blockIdx.x;    // sample
    const int tid = threadIdx.x;   // gate row 0..511

    __shared__ __align__(16) uint32_t h1p[HDIM / 2];  // h1 as bf16 pairs
    __shared__ __align__(16) uint32_t h2p[HDIM / 2];  // h2 as bf16 pairs
    __shared__ float gact[NT];                        // activated gates
    __shared__ float h2f[HDIM];                       // fp32 h2 for output dot

    // ---- one-time: load this thread's weight rows, quantize to bf16 pairs (registers)
    uint32_t w1[HDIM / 2], w2[HDIM / 2], w3[HDIM / 2];
    {
        const float2* r1 = (const float2*)(W_hh1 + tid * HDIM);
        const float2* r2 = (const float2*)(W_ih2 + tid * HDIM);
        const float2* r3 = (const float2*)(W_hh2 + tid * HDIM);
#pragma unroll
        for (int k = 0; k < HDIM / 2; k++) {
            float2 e1 = r1[k]; w1[k] = pack2(e1.x, e1.y);
            float2 e2 = r2[k]; w2[k] = pack2(e2.x, e2.y);
            float2 e3 = r3[k]; w3[k] = pack2(e3.x, e3.y);
        }
    }
    const float bias1 = b_ih1[tid] + b_hh1[tid];
    const float bias2 = b_ih2[tid] + b_hh2[tid];
    const float wih1  = W_ih1[tid];
    const int   sec   = tid >> 7;   // 0:i 1:f 2:g 3:o
    float wo0 = 0.f, wo1 = 0.f;
    if (tid < 64) { wo0 = W_out[tid]; wo1 = W_out[tid + 64]; }
    const float bo = b_out[0];

    float c1 = 0.f, c2 = 0.f;       // live in threads 0..127

    if (tid < HDIM / 2) { h1p[tid] = 0u; h2p[tid] = 0u; }
    __syncthreads();

    const float* xb = x + b * T_STEPS;
    float*       ob = out + b * T_STEPS;
    float x_cur = xb[0];

    for (int t = 0; t < T_STEPS; t++) {
        // prefetch next step's x early (hide global latency)
        float x_nxt = xb[(t + 1 < T_STEPS) ? (t + 1) : t];

        // ---------- phase 1: layer-1 gate preactivation (row tid)
        float a1 = fmaf(x_cur, wih1, bias1);
        {
            const uint4* Hv = (const uint4*)h1p;
#pragma unroll
            for (int j = 0; j < HDIM / 8; j++) {
                uint4 p = Hv[j];
                a1 = dot2_bf16(w1[4 * j + 0], p.x, a1);
                a1 = dot2_bf16(w1[4 * j + 1], p.y, a1);
                a1 = dot2_bf16(w1[4 * j + 2], p.z, a1);
                a1 = dot2_bf16(w1[4 * j + 3], p.w, a1);
            }
        }
        gact[tid] = (sec == 2) ? tanhf_(a1) : sigmoidf_(a1);
        __syncthreads();   // barrier 1

        // ---------- layer-1 state update (threads 0..127, c1 in registers)
        if (tid < HDIM) {
            float gi = gact[tid], gf = gact[tid + 128];
            float gg = gact[tid + 256], go = gact[tid + 384];
            c1 = fmaf(gf, c1, gi * gg);
            float h1 = go * tanhf_(c1);
            ((uint16_t*)h1p)[tid] = f2bf(h1);
        }
        __syncthreads();   // barrier 2

        // ---------- phase 2: layer-2 gate preactivation (row tid)
        float a2 = bias2, a3 = 0.f;
        {
            const uint4* H1v = (const uint4*)h1p;
            const uint4* H2v = (const uint4*)h2p;
#pragma unroll
            for (int j = 0; j < HDIM / 8; j++) {
                uint4 p = H1v[j];
                a2 = dot2_bf16(w2[4 * j + 0], p.x, a2);
                a2 = dot2_bf16(w2[4 * j + 1], p.y, a2);
                a2 = dot2_bf16(w2[4 * j + 2], p.z, a2);
                a2 = dot2_bf16(w2[4 * j + 3], p.w, a2);
                uint4 q = H2v[j];
                a3 = dot2_bf16(w3[4 * j + 0], q.x, a3);
                a3 = dot2_bf16(w3[4 * j + 1], q.y, a3);
                a3 = dot2_bf16(w3[4 * j + 2], q.z, a3);
                a3 = dot2_bf16(w3[4 * j + 3], q.w, a3);
            }
        }
        float g2 = a2 + a3;
        gact[tid] = (sec == 2) ? tanhf_(g2) : sigmoidf_(g2);
        __syncthreads();   // barrier 3

        // ---------- layer-2 state update
        if (tid < HDIM) {
            float gi = gact[tid], gf = gact[tid + 128];
            float gg = gact[tid + 256], go = gact[tid + 384];
            c2 = fmaf(gf, c2, gi * gg);
            float h2 = go * tanhf_(c2);
            ((uint16_t*)h2p)[tid] = f2bf(h2);
            h2f[tid] = h2;
        }
        __syncthreads();   // barrier 4

        // ---------- output: out[b,t] = W_out . h2 + b_out   (wave 0 only)
        if (tid < 64) {
            float p = fmaf(wo0, h2f[tid], wo1 * h2f[tid + 64]);
#pragma unroll
            for (int off = 32; off > 0; off >>= 1)
                p += __shfl_down(p, off, 64);
            if (tid == 0) ob[t] = p + bo;
        }
        x_cur = x_nxt;
    }
}

extern "C" void kernel_launch(void* const* d_in, const int* in_sizes, int n_in,
                              void* d_out, int out_size, void* d_ws, size_t ws_size,
                              hipStream_t stream) {
    const float* x     = (const float*)d_in[0];
    const float* W_ih1 = (const float*)d_in[1];
    const float* W_hh1 = (const float*)d_in[2];
    const float* b_ih1 = (const float*)d_in[3];
    const float* b_hh1 = (const float*)d_in[4];
    const float* W_ih2 = (const float*)d_in[5];
    const float* W_hh2 = (const float*)d_in[6];
    const float* b_ih2 = (const float*)d_in[7];
    const float* b_hh2 = (const float*)d_in[8];
    const float* W_out = (const float*)d_in[9];
    const float* b_out = (const float*)d_in[10];
    float* out = (float*)d_out;

    const int B = in_sizes[0] / T_STEPS;   // 256
    hipLaunchKernelGGL(lstm_persistent, dim3(B), dim3(NT), 0, stream,
                       x, W_ih1, W_hh1, b_ih1, b_hh1,
                       W_ih2, W_hh2, b_ih2, b_hh2, W_out, b_out, out);
}

// Round 2
// 1951.211 us; speedup vs baseline: 1.0022x; 1.0022x over previous
//
#include <hip/hip_runtime.h>
#include <stdint.h>

#define T_STEPS 1024
#define HDIM    128
#define NT      512   // threads per block = 4*H gate rows

typedef __bf16 v2bf __attribute__((ext_vector_type(2)));

// d = a0*b0 + a1*b1 + c, operands are bf16 pairs packed in uint32 (elem0 = low 16)
__device__ __forceinline__ float dot2_bf16(uint32_t a, uint32_t b, float c) {
#if defined(__HIP_DEVICE_COMPILE__) && __has_builtin(__builtin_amdgcn_fdot2_f32_bf16)
    union U { uint32_t u; v2bf v; };
    U ua, ub; ua.u = a; ub.u = b;
    return __builtin_amdgcn_fdot2_f32_bf16(ua.v, ub.v, c, false);
#else
    float a0 = __uint_as_float(a << 16);
    float a1 = __uint_as_float(a & 0xFFFF0000u);
    float b0 = __uint_as_float(b << 16);
    float b1 = __uint_as_float(b & 0xFFFF0000u);
    return fmaf(a1, b1, fmaf(a0, b0, c));
#endif
}

__device__ __forceinline__ uint16_t f2bf(float f) {  // round-to-nearest-even
    uint32_t u = __float_as_uint(f);
    u += 0x7FFFu + ((u >> 16) & 1u);
    return (uint16_t)(u >> 16);
}
__device__ __forceinline__ uint32_t pack2(float lo, float hi) {
    return (uint32_t)f2bf(lo) | ((uint32_t)f2bf(hi) << 16);
}
__device__ __forceinline__ float sigmoidf_(float x) {
    return 1.0f / (1.0f + __expf(-x));
}
__device__ __forceinline__ float tanhf_(float x) {
    return 1.0f - 2.0f / (__expf(2.0f * x) + 1.0f);
}

// __launch_bounds__(512, 2): 2 waves/EU * 4 EU = 8 waves = exactly one
// 512-thread block per CU -> VGPR cap 256. Without the ",2" the compiler
// targeted 4 waves/EU (cap 128) and spilled the 192 packed-weight VGPRs to
// scratch: R0 rocprof showed WRITE_SIZE=105MB (spill writes), VALUBusy=43%.
__global__ __launch_bounds__(NT, 2) void lstm_persistent(
    const float* __restrict__ x,
    const float* __restrict__ W_ih1, const float* __restrict__ W_hh1,
    const float* __restrict__ b_ih1, const float* __restrict__ b_hh1,
    const float* __restrict__ W_ih2, const float* __restrict__ W_hh2,
    const float* __restrict__ b_ih2, const float* __restrict__ b_hh2,
    const float* __restrict__ W_out, const float* __restrict__ b_out,
    float* __restrict__ out)
{
    const int b   = blockIdx.x;    // sample
    const int tid = threadIdx.x;   // gate row 0..511

    __shared__ __align__(16) uint32_t h1p[HDIM / 2];  // h1 as bf16 pairs
    __shared__ __align__(16) uint32_t h2p[HDIM / 2];  // h2 as bf16 pairs
    __shared__ float gact[NT];                        // activated gates
    __shared__ float h2f[HDIM];                       // fp32 h2 for output dot

    // ---- one-time: load this thread's weight rows, quantize to bf16 pairs (registers)
    uint32_t w1[HDIM / 2], w2[HDIM / 2], w3[HDIM / 2];
    {
        const float2* r1 = (const float2*)(W_hh1 + tid * HDIM);
        const float2* r2 = (const float2*)(W_ih2 + tid * HDIM);
        const float2* r3 = (const float2*)(W_hh2 + tid * HDIM);
#pragma unroll
        for (int k = 0; k < HDIM / 2; k++) {
            float2 e1 = r1[k]; w1[k] = pack2(e1.x, e1.y);
            float2 e2 = r2[k]; w2[k] = pack2(e2.x, e2.y);
            float2 e3 = r3[k]; w3[k] = pack2(e3.x, e3.y);
        }
    }
    const float bias1 = b_ih1[tid] + b_hh1[tid];
    const float bias2 = b_ih2[tid] + b_hh2[tid];
    const float wih1  = W_ih1[tid];
    const int   sec   = tid >> 7;   // 0:i 1:f 2:g 3:o
    float wo0 = 0.f, wo1 = 0.f;
    if (tid < 64) { wo0 = W_out[tid]; wo1 = W_out[tid + 64]; }
    const float bo = b_out[0];

    float c1 = 0.f, c2 = 0.f;       // live in threads 0..127

    if (tid < HDIM / 2) { h1p[tid] = 0u; h2p[tid] = 0u; }
    __syncthreads();

    const float* xb = x + b * T_STEPS;
    float*       ob = out + b * T_STEPS;
    float x_cur = xb[0];

    for (int t = 0; t < T_STEPS; t++) {
        // prefetch next step's x early (hide global latency)
        float x_nxt = xb[(t + 1 < T_STEPS) ? (t + 1) : t];

        // ---------- phase 1: layer-1 gate preactivation (row tid)
        float a1 = fmaf(x_cur, wih1, bias1);
        {
            const uint4* Hv = (const uint4*)h1p;
#pragma unroll
            for (int j = 0; j < HDIM / 8; j++) {
                uint4 p = Hv[j];
                a1 = dot2_bf16(w1[4 * j + 0], p.x, a1);
                a1 = dot2_bf16(w1[4 * j + 1], p.y, a1);
                a1 = dot2_bf16(w1[4 * j + 2], p.z, a1);
                a1 = dot2_bf16(w1[4 * j + 3], p.w, a1);
            }
        }
        gact[tid] = (sec == 2) ? tanhf_(a1) : sigmoidf_(a1);
        __syncthreads();   // barrier 1

        // ---------- layer-1 state update (threads 0..127, c1 in registers)
        if (tid < HDIM) {
            float gi = gact[tid], gf = gact[tid + 128];
            float gg = gact[tid + 256], go = gact[tid + 384];
            c1 = fmaf(gf, c1, gi * gg);
            float h1 = go * tanhf_(c1);
            ((uint16_t*)h1p)[tid] = f2bf(h1);
        }
        __syncthreads();   // barrier 2

        // ---------- phase 2: layer-2 gate preactivation (row tid)
        float a2 = bias2, a3 = 0.f;
        {
            const uint4* H1v = (const uint4*)h1p;
            const uint4* H2v = (const uint4*)h2p;
#pragma unroll
            for (int j = 0; j < HDIM / 8; j++) {
                uint4 p = H1v[j];
                a2 = dot2_bf16(w2[4 * j + 0], p.x, a2);
                a2 = dot2_bf16(w2[4 * j + 1], p.y, a2);
                a2 = dot2_bf16(w2[4 * j + 2], p.z, a2);
                a2 = dot2_bf16(w2[4 * j + 3], p.w, a2);
                uint4 q = H2v[j];
                a3 = dot2_bf16(w3[4 * j + 0], q.x, a3);
                a3 = dot2_bf16(w3[4 * j + 1], q.y, a3);
                a3 = dot2_bf16(w3[4 * j + 2], q.z, a3);
                a3 = dot2_bf16(w3[4 * j + 3], q.w, a3);
            }
        }
        float g2 = a2 + a3;
        gact[tid] = (sec == 2) ? tanhf_(g2) : sigmoidf_(g2);
        __syncthreads();   // barrier 3

        // ---------- layer-2 state update
        if (tid < HDIM) {
            float gi = gact[tid], gf = gact[tid + 128];
            float gg = gact[tid + 256], go = gact[tid + 384];
            c2 = fmaf(gf, c2, gi * gg);
            float h2 = go * tanhf_(c2);
            ((uint16_t*)h2p)[tid] = f2bf(h2);
            h2f[tid] = h2;
        }
        __syncthreads();   // barrier 4

        // ---------- output: out[b,t] = W_out . h2 + b_out   (wave 0 only)
        if (tid < 64) {
            float p = fmaf(wo0, h2f[tid], wo1 * h2f[tid + 64]);
#pragma unroll
            for (int off = 32; off > 0; off >>= 1)
                p += __shfl_down(p, off, 64);
            if (tid == 0) ob[t] = p + bo;
        }
        x_cur = x_nxt;
    }
}

extern "C" void kernel_launch(void* const* d_in, const int* in_sizes, int n_in,
                              void* d_out, int out_size, void* d_ws, size_t ws_size,
                              hipStream_t stream) {
    const float* x     = (const float*)d_in[0];
    const float* W_ih1 = (const float*)d_in[1];
    const float* W_hh1 = (const float*)d_in[2];
    const float* b_ih1 = (const float*)d_in[3];
    const float* b_hh1 = (const float*)d_in[4];
    const float* W_ih2 = (const float*)d_in[5];
    const float* W_hh2 = (const float*)d_in[6];
    const float* b_ih2 = (const float*)d_in[7];
    const float* b_hh2 = (const float*)d_in[8];
    const float* W_out = (const float*)d_in[9];
    const float* b_out = (const float*)d_in[10];
    float* out = (float*)d_out;

    const int B = in_sizes[0] / T_STEPS;   // 256
    hipLaunchKernelGGL(lstm_persistent, dim3(B), dim3(NT), 0, stream,
                       x, W_ih1, W_hh1, b_ih1, b_hh1,
                       W_ih2, W_hh2, b_ih2, b_hh2, W_out, b_out, out);
}

// Round 3
// 1927.614 us; speedup vs baseline: 1.0145x; 1.0122x over previous
//
#include <hip/hip_runtime.h>
#include <hip/hip_fp16.h>
#include <stdint.h>

#define T_STEPS 1024
#define HDIM    128
#define NT      512   // threads per block = 4*H gate rows

// ---- packed f16-pair types --------------------------------------------------
typedef _Float16 v2h  __attribute__((ext_vector_type(2)));
typedef unsigned int u16x __attribute__((ext_vector_type(16)));  // 16 f16-pairs

union HU { uint32_t u; v2h v; };

// d = a0*b0 + a1*b1 + c  (f16 inputs, f32 accumulate) -> v_dot2_f32_f16
__device__ __forceinline__ float dot2h(uint32_t a, uint32_t b, float c) {
    HU ua, ub; ua.u = a; ub.u = b;
    return __builtin_amdgcn_fdot2(ua.v, ub.v, c, false);
}

__device__ __forceinline__ uint32_t packh2f(float2 e) {
    return (uint32_t)__half_as_ushort(__float2half_rn(e.x)) |
           ((uint32_t)__half_as_ushort(__float2half_rn(e.y)) << 16);
}
__device__ __forceinline__ uint16_t f2h(float f) {
    return __half_as_ushort(__float2half_rn(f));
}
__device__ __forceinline__ float sigmoidf_(float x) {
    return 1.0f / (1.0f + __expf(-x));
}
__device__ __forceinline__ float tanhf_(float x) {
    return 1.0f - 2.0f / (__expf(2.0f * x) + 1.0f);
}

// Load quarter q (16 f16-pairs = 32 floats) of a weight row into a named
// ext-vector SSA value. Constant indices only — no alloca is ever created,
// so the weights CANNOT fall to scratch (R1 lesson: uint32_t w[64] arrays
// were never promoted; 105 MB/dispatch spill traffic at LLC BW = 2 ms).
#define SETW(W, rowptr, q) do {                                            \
    const float2* _r = ((const float2*)(rowptr)) + 16 * (q);               \
    W[0]  = packh2f(_r[0]);  W[1]  = packh2f(_r[1]);                       \
    W[2]  = packh2f(_r[2]);  W[3]  = packh2f(_r[3]);                       \
    W[4]  = packh2f(_r[4]);  W[5]  = packh2f(_r[5]);                       \
    W[6]  = packh2f(_r[6]);  W[7]  = packh2f(_r[7]);                       \
    W[8]  = packh2f(_r[8]);  W[9]  = packh2f(_r[9]);                       \
    W[10] = packh2f(_r[10]); W[11] = packh2f(_r[11]);                      \
    W[12] = packh2f(_r[12]); W[13] = packh2f(_r[13]);                      \
    W[14] = packh2f(_r[14]); W[15] = packh2f(_r[15]);                      \
} while (0)

// 16 dot2s of one weight-quarter against h pairs [32q, 32q+32) read from LDS.
#define DOT_Q(W, Hv, q, acc) do {                                          \
    uint4 _p0 = (Hv)[4*(q)+0], _p1 = (Hv)[4*(q)+1];                        \
    uint4 _p2 = (Hv)[4*(q)+2], _p3 = (Hv)[4*(q)+3];                        \
    acc = dot2h(W[0],  _p0.x, acc); acc = dot2h(W[1],  _p0.y, acc);        \
    acc = dot2h(W[2],  _p0.z, acc); acc = dot2h(W[3],  _p0.w, acc);        \
    acc = dot2h(W[4],  _p1.x, acc); acc = dot2h(W[5],  _p1.y, acc);        \
    acc = dot2h(W[6],  _p1.z, acc); acc = dot2h(W[7],  _p1.w, acc);        \
    acc = dot2h(W[8],  _p2.x, acc); acc = dot2h(W[9],  _p2.y, acc);        \
    acc = dot2h(W[10], _p2.z, acc); acc = dot2h(W[11], _p2.w, acc);        \
    acc = dot2h(W[12], _p3.x, acc); acc = dot2h(W[13], _p3.y, acc);        \
    acc = dot2h(W[14], _p3.z, acc); acc = dot2h(W[15], _p3.w, acc);        \
} while (0)

// __launch_bounds__(512, 2): 2 waves/EU = one 512-thread block/CU -> VGPR
// cap 256. Needed: 12x16 = 192 weight VGPRs + ~40 working set.
__global__ __launch_bounds__(NT, 2) void lstm_persistent(
    const float* __restrict__ x,
    const float* __restrict__ W_ih1, const float* __restrict__ W_hh1,
    const float* __restrict__ b_ih1, const float* __restrict__ b_hh1,
    const float* __restrict__ W_ih2, const float* __restrict__ W_hh2,
    const float* __restrict__ b_ih2, const float* __restrict__ b_hh2,
    const float* __restrict__ W_out, const float* __restrict__ b_out,
    float* __restrict__ out)
{
    const int b   = blockIdx.x;    // sample
    const int tid = threadIdx.x;   // gate row 0..511

    __shared__ __align__(16) uint32_t h1p[HDIM / 2];  // h1 as f16 pairs
    __shared__ __align__(16) uint32_t h2p[HDIM / 2];  // h2 as f16 pairs
    __shared__ float gact[NT];                        // activated gates
    __shared__ float h2f[HDIM];                       // fp32 h2 for output dot

    // ---- one-time: this thread's weight rows as 12 named vector SSA values
    u16x w1a, w1b, w1c, w1d, w2a, w2b, w2c, w2d, w3a, w3b, w3c, w3d;
    {
        const float* r1 = W_hh1 + tid * HDIM;
        const float* r2 = W_ih2 + tid * HDIM;
        const float* r3 = W_hh2 + tid * HDIM;
        SETW(w1a, r1, 0); SETW(w1b, r1, 1); SETW(w1c, r1, 2); SETW(w1d, r1, 3);
        SETW(w2a, r2, 0); SETW(w2b, r2, 1); SETW(w2c, r2, 2); SETW(w2d, r2, 3);
        SETW(w3a, r3, 0); SETW(w3b, r3, 1); SETW(w3c, r3, 2); SETW(w3d, r3, 3);
    }
    const float bias1 = b_ih1[tid] + b_hh1[tid];
    const float bias2 = b_ih2[tid] + b_hh2[tid];
    const float wih1  = W_ih1[tid];
    const int   sec   = tid >> 7;   // 0:i 1:f 2:g 3:o
    float wo0 = 0.f, wo1 = 0.f;
    if (tid < 64) { wo0 = W_out[tid]; wo1 = W_out[tid + 64]; }
    const float bo = b_out[0];

    float c1 = 0.f, c2 = 0.f;       // live in threads 0..127

    if (tid < HDIM / 2) { h1p[tid] = 0u; h2p[tid] = 0u; }
    __syncthreads();

    const float* xb = x + b * T_STEPS;
    float*       ob = out + b * T_STEPS;
    float x_cur = xb[0];

    for (int t = 0; t < T_STEPS; t++) {
        float x_nxt = xb[(t + 1 < T_STEPS) ? (t + 1) : t];

        // ---------- phase 1: layer-1 gate preactivation (row tid)
        // 4 accumulator chains: 2 waves/SIMD need >=2 indep chains to cover
        // the ~4-cyc dot2 dependency latency.
        const uint4* Hv1 = (const uint4*)h1p;
        float aA = fmaf(x_cur, wih1, bias1), aB = 0.f, aC = 0.f, aD = 0.f;
        DOT_Q(w1a, Hv1, 0, aA); DOT_Q(w1b, Hv1, 1, aB);
        DOT_Q(w1c, Hv1, 2, aC); DOT_Q(w1d, Hv1, 3, aD);
        float a1 = (aA + aB) + (aC + aD);
        gact[tid] = (sec == 2) ? tanhf_(a1) : sigmoidf_(a1);
        __syncthreads();   // barrier 1

        // ---------- layer-1 state update (threads 0..127, c1 in registers)
        if (tid < HDIM) {
            float gi = gact[tid], gf = gact[tid + 128];
            float gg = gact[tid + 256], go = gact[tid + 384];
            c1 = fmaf(gf, c1, gi * gg);
            float h1 = go * tanhf_(c1);
            ((uint16_t*)h1p)[tid] = f2h(h1);
        }
        __syncthreads();   // barrier 2

        // ---------- phase 2: layer-2 gate preactivation (row tid)
        const uint4* Hv2 = (const uint4*)h2p;
        float bA = bias2, bB = 0.f, bC = 0.f, bD = 0.f;
        DOT_Q(w2a, Hv1, 0, bA); DOT_Q(w3a, Hv2, 0, bB);
        DOT_Q(w2b, Hv1, 1, bC); DOT_Q(w3b, Hv2, 1, bD);
        DOT_Q(w2c, Hv1, 2, bA); DOT_Q(w3c, Hv2, 2, bB);
        DOT_Q(w2d, Hv1, 3, bC); DOT_Q(w3d, Hv2, 3, bD);
        float g2 = (bA + bB) + (bC + bD);
        gact[tid] = (sec == 2) ? tanhf_(g2) : sigmoidf_(g2);
        __syncthreads();   // barrier 3

        // ---------- layer-2 state update
        if (tid < HDIM) {
            float gi = gact[tid], gf = gact[tid + 128];
            float gg = gact[tid + 256], go = gact[tid + 384];
            c2 = fmaf(gf, c2, gi * gg);
            float h2 = go * tanhf_(c2);
            ((uint16_t*)h2p)[tid] = f2h(h2);
            h2f[tid] = h2;
        }
        __syncthreads();   // barrier 4

        // ---------- output: out[b,t] = W_out . h2 + b_out   (wave 0 only)
        if (tid < 64) {
            float p = fmaf(wo0, h2f[tid], wo1 * h2f[tid + 64]);
#pragma unroll
            for (int off = 32; off > 0; off >>= 1)
                p += __shfl_down(p, off, 64);
            if (tid == 0) ob[t] = p + bo;
        }
        x_cur = x_nxt;
    }
}

extern "C" void kernel_launch(void* const* d_in, const int* in_sizes, int n_in,
                              void* d_out, int out_size, void* d_ws, size_t ws_size,
                              hipStream_t stream) {
    const float* x     = (const float*)d_in[0];
    const float* W_ih1 = (const float*)d_in[1];
    const float* W_hh1 = (const float*)d_in[2];
    const float* b_ih1 = (const float*)d_in[3];
    const float* b_hh1 = (const float*)d_in[4];
    const float* W_ih2 = (const float*)d_in[5];
    const float* W_hh2 = (const float*)d_in[6];
    const float* b_ih2 = (const float*)d_in[7];
    const float* b_hh2 = (const float*)d_in[8];
    const float* W_out = (const float*)d_in[9];
    const float* b_out = (const float*)d_in[10];
    float* out = (float*)d_out;

    const int B = in_sizes[0] / T_STEPS;   // 256
    hipLaunchKernelGGL(lstm_persistent, dim3(B), dim3(NT), 0, stream,
                       x, W_ih1, W_hh1, b_ih1, b_hh1,
                       W_ih2, W_hh2, b_ih2, b_hh2, W_out, b_out, out);
}